// Round 8
// baseline (644.100 us; speedup 1.0000x reference)
//
#include <hip/hip_runtime.h>

#define XDIM 512
#define CDIM 32
#define NPIX (XDIM * XDIM)
#define NB 8

typedef short bf16x8 __attribute__((ext_vector_type(8)));
typedef float f32x4 __attribute__((ext_vector_type(4)));
typedef float f32x16 __attribute__((ext_vector_type(16)));

#define FEATS_BYTES (NPIX * CDIM * 4)   // 33.5 MB

__device__ __forceinline__ short f2bf(float v) {
    __bf16 b = (__bf16)v;
    return __builtin_bit_cast(short, b);
}
__device__ __forceinline__ float bfup(short s) {
    return (float)__builtin_bit_cast(__bf16, s);
}

// ---------------------------------------------------------------------------
// Weight prep (identical to R3/R5/R6). L=3 (render layer 1) is now unused by
// the hot kernel (folded into y_kernel) but kept for layout stability.
// ---------------------------------------------------------------------------
__global__ __launch_bounds__(64) void wprep_kernel(
    const float* __restrict__ w_h, const float* __restrict__ r_wh,
    unsigned short* __restrict__ afrag)
{
    int L = blockIdx.x >> 1;
    int T = blockIdx.x & 1;
    int l = threadIdx.x;
    const float* W = (L < 3) ? (w_h + L * CDIM * CDIM) : (r_wh + (L - 3) * CDIM * CDIM);
    int m = l & 31;
    int h = l >> 5;
    unsigned short* dh = afrag + (((L * 2 + T) * 2 + 0) * 64 + l) * 8;
    unsigned short* dl = afrag + (((L * 2 + T) * 2 + 1) * 64 + l) * 8;
    for (int j = 0; j < 8; j++) {
        int c = 16 * T + 4 * h + (j & 3) + 8 * (j >> 2);
        float v = W[c * CDIM + m];
        short hi = f2bf(v);
        short lo = f2bf(v - bfup(hi));
        dh[j] = (unsigned short)hi;
        dl[j] = (unsigned short)lo;
    }
}

__global__ __launch_bounds__(256) void feats_kernel(
    const float* __restrict__ data, const float* __restrict__ lerp_w,
    const int* __restrict__ x0, const int* __restrict__ y0,
    const int* __restrict__ x1, const int* __restrict__ y1,
    float* __restrict__ feats)
{
    int tid = blockIdx.x * 256 + threadIdx.x;
    int p = tid >> 5;
    int c = tid & 31;
    if (p >= NPIX) return;
    float wA = lerp_w[p * 2 + 0];
    float wB = lerp_w[p * 2 + 1];
    int xa = x0[p], ya = y0[p], xb = x1[p], yb = y1[p];
    float v00 = data[(ya * XDIM + xa) * CDIM + c];
    float v01 = data[(ya * XDIM + xb) * CDIM + c];
    float v10 = data[(yb * XDIM + xa) * CDIM + c];
    float v11 = data[(yb * XDIM + xb) * CDIM + c];
    float r = v00 * (1.f - wA) * (1.f - wB) + v01 * wA * (1.f - wB)
            + v10 * (1.f - wA) * wB + v11 * wA * wB;
    feats[p * CDIM + c] = r;
}

// ---------------------------------------------------------------------------
// Y-fold: feats[p] <- r_wh[0]^T @ feats[p], in place, exact fp32.
// Pointwise in p; each pixel's 32 threads live in one wave (lockstep), and
// per-lane program order guarantees all reads complete before the store.
// After this, gathering Y and weighting by bilinear coeffs yields render
// layer 1's pre-activation exactly (linearity), so the hot kernel skips
// one full build2+MFMA layer.
// ---------------------------------------------------------------------------
__global__ __launch_bounds__(256) void y_kernel(
    const float* __restrict__ r_wh, float* __restrict__ feats)
{
    int tid = blockIdx.x * 256 + threadIdx.x;
    int p = tid >> 5;
    int c = tid & 31;
    const float* f = feats + p * CDIM;
    float acc = 0.f;
    #pragma unroll
    for (int k = 0; k < CDIM; k++)
        acc = fmaf(f[k], r_wh[k * CDIM + c], acc);
    feats[p * CDIM + c] = acc;
}

// ---------------------------------------------------------------------------
// Hot kernel helpers (R6 math).
// ---------------------------------------------------------------------------
__device__ __forceinline__ void build2(const float a[16], bf16x8 bh[2], bf16x8 bl[2]) {
    #pragma unroll
    for (int r = 0; r < 16; r++) {
        short hi = f2bf(a[r]);
        bh[r >> 3][r & 7] = hi;
        bl[r >> 3][r & 7] = f2bf(a[r] - bfup(hi));
    }
}

__device__ __forceinline__ void matmul_split(
    const bf16x8 fh[2], const bf16x8 fl[2],
    const bf16x8 bh[2], const bf16x8 bl[2],
    f32x16& accA, f32x16& accB)
{
    f32x16 z = {0.f, 0.f, 0.f, 0.f, 0.f, 0.f, 0.f, 0.f,
                0.f, 0.f, 0.f, 0.f, 0.f, 0.f, 0.f, 0.f};
    accA = z; accB = z;
    __builtin_amdgcn_s_setprio(1);
    accA = __builtin_amdgcn_mfma_f32_32x32x16_bf16(fl[0], bh[0], accA, 0, 0, 0);
    accB = __builtin_amdgcn_mfma_f32_32x32x16_bf16(fl[1], bh[1], accB, 0, 0, 0);
    accA = __builtin_amdgcn_mfma_f32_32x32x16_bf16(fh[0], bl[0], accA, 0, 0, 0);
    accB = __builtin_amdgcn_mfma_f32_32x32x16_bf16(fh[1], bl[1], accB, 0, 0, 0);
    accA = __builtin_amdgcn_mfma_f32_32x32x16_bf16(fh[0], bh[0], accA, 0, 0, 0);
    accB = __builtin_amdgcn_mfma_f32_32x32x16_bf16(fh[1], bh[1], accB, 0, 0, 0);
    __builtin_amdgcn_s_setprio(0);
}

__device__ __forceinline__ void warp_layer(
    float a[16], const bf16x8 fh[2], const bf16x8 fl[2],
    const float* __restrict__ bias, const float* __restrict__ gamma,
    const float* __restrict__ beta, int h)
{
    bf16x8 bh[2], bl[2];
    build2(a, bh, bl);
    f32x16 accA, accB;
    matmul_split(fh, fl, bh, bl, accA, accB);

    float sum = 0.f, sq = 0.f;
    #pragma unroll
    for (int g = 0; g < 4; g++) {
        f32x4 bia = *(const f32x4*)(bias + 8 * g + 4 * h);
        #pragma unroll
        for (int i = 0; i < 4; i++) {
            int r = 4 * g + i;
            float v = (accA[r] + accB[r]) + bia[i];
            a[r] = v;
            sum += v;
            sq = fmaf(v, v, sq);
        }
    }
    sum += __shfl_xor(sum, 32, 64);
    sq  += __shfl_xor(sq, 32, 64);
    float mu = sum * (1.f / 32.f);
    float var = fmaf(sq, 1.f / 32.f, -mu * mu);
    float rs = rsqrtf(var + 1e-5f);
    #pragma unroll
    for (int g = 0; g < 4; g++) {
        f32x4 gg = *(const f32x4*)(gamma + 8 * g + 4 * h);
        f32x4 be = *(const f32x4*)(beta + 8 * g + 4 * h);
        #pragma unroll
        for (int i = 0; i < 4; i++) {
            int r = 4 * g + i;
            a[r] = __sinf(fmaf((a[r] - mu) * rs, gg[i], be[i]));
        }
    }
}

__device__ __forceinline__ void render_layer(
    float a[16], const bf16x8 fh[2], const bf16x8 fl[2],
    const float* __restrict__ bias, int h)
{
    bf16x8 bh[2], bl[2];
    build2(a, bh, bl);
    f32x16 accA, accB;
    matmul_split(fh, fl, bh, bl, accA, accB);
    #pragma unroll
    for (int g = 0; g < 4; g++) {
        f32x4 bia = *(const f32x4*)(bias + 8 * g + 4 * h);
        #pragma unroll
        for (int i = 0; i < 4; i++) {
            int r = 4 * g + i;
            a[r] = fmaxf((accA[r] + accB[r]) + bia[i], 0.f);
        }
    }
}

#define LOADFRAG(L, FH, FL) do { \
    FH[0] = ap[(((L) * 2 + 0) * 2 + 0) * 64 + lane]; \
    FL[0] = ap[(((L) * 2 + 0) * 2 + 1) * 64 + lane]; \
    FH[1] = ap[(((L) * 2 + 1) * 2 + 0) * 64 + lane]; \
    FL[1] = ap[(((L) * 2 + 1) * 2 + 1) * 64 + lane]; \
} while (0)

__global__ __launch_bounds__(256, 4) void fused_mfma_kernel(
    const float* __restrict__ t, const float* __restrict__ xy_basis,
    const float* __restrict__ w_in, const float* __restrict__ b_in,
    const float* __restrict__ b_h,
    const float* __restrict__ ln_g, const float* __restrict__ ln_b,
    const float* __restrict__ w_out, const float* __restrict__ b_out,
    const float* __restrict__ r_bh,
    const float* __restrict__ r_wo, const float* __restrict__ r_bo,
    const float* __restrict__ yimg, const unsigned short* __restrict__ afrag,
    float* __restrict__ out)
{
    int lane = threadIdx.x & 63;
    int p = lane & 31, h = lane >> 5;

    // XCD-chunked swizzle (identical to R3/R5/R6).
    int bid = blockIdx.x;
    int swz = (bid & 7) * 2048 + (bid >> 3);
    int gw = swz * 4 + (int)(threadIdx.x >> 6);
    int b = gw & 7;
    int pbase = (gw >> 3) << 5;
    int pix = pbase + p;

    const bf16x8* ap = (const bf16x8*)afrag;

    bf16x8 fAh[2], fAl[2], fBh[2], fBl[2], fCh[2], fCl[2];
    LOADFRAG(0, fAh, fAl);
    LOADFRAG(1, fBh, fBl);

    float alpha = t[b] + 0.5f;
    float2 xy = ((const float2*)xy_basis)[pix];

    // ---- input layer ----
    float a[16];
    #pragma unroll
    for (int g = 0; g < 4; g++) {
        int c = 8 * g + 4 * h;
        f32x4 w0 = *(const f32x4*)(w_in + c);
        f32x4 w1 = *(const f32x4*)(w_in + CDIM + c);
        f32x4 w2 = *(const f32x4*)(w_in + 2 * CDIM + c);
        f32x4 bb = *(const f32x4*)(b_in + c);
        #pragma unroll
        for (int i = 0; i < 4; i++)
            a[4 * g + i] = fmaf(xy.x, w0[i], fmaf(xy.y, w1[i], fmaf(alpha, w2[i], bb[i])));
    }

    // ---- 3 warp layers ----
    warp_layer(a, fAh, fAl, b_h + 0 * CDIM, ln_g + 0 * CDIM, ln_b + 0 * CDIM, h);
    LOADFRAG(2, fCh, fCl);
    warp_layer(a, fBh, fBl, b_h + 1 * CDIM, ln_g + 1 * CDIM, ln_b + 1 * CDIM, h);
    warp_layer(a, fCh, fCl, b_h + 2 * CDIM, ln_g + 2 * CDIM, ln_b + 2 * CDIM, h);

    // ---- motion head ----
    float mx = 0.f, my = 0.f;
    #pragma unroll
    for (int g = 0; g < 4; g++) {
        int c = 8 * g + 4 * h;
        f32x4 wa = *(const f32x4*)(w_out + 2 * c);
        f32x4 wb = *(const f32x4*)(w_out + 2 * c + 4);
        mx = fmaf(a[4 * g + 0], wa[0], mx); my = fmaf(a[4 * g + 0], wa[1], my);
        mx = fmaf(a[4 * g + 1], wa[2], mx); my = fmaf(a[4 * g + 1], wa[3], my);
        mx = fmaf(a[4 * g + 2], wb[0], mx); my = fmaf(a[4 * g + 2], wb[1], my);
        mx = fmaf(a[4 * g + 3], wb[2], mx); my = fmaf(a[4 * g + 3], wb[3], my);
    }
    mx += __shfl_xor(mx, 32, 64);
    my += __shfl_xor(my, 32, 64);
    float gridx = fmaf(mx + b_out[0], 0.1f, xy.x);
    float gridy = fmaf(my + b_out[1], 0.1f, xy.y);

    // ---- remaining render-layer fragments (L=4,5): overlap with gather ----
    bf16x8 r1h[2], r1l[2], r2h[2], r2l[2];
    LOADFRAG(4, r1h, r1l);
    LOADFRAG(5, r2h, r2l);

    // ---- gather on Y: weighted sum IS render layer 1's pre-activation ----
    float ix = ((gridx + 1.0f) * (float)XDIM - 1.0f) * 0.5f;
    float iy = ((gridy + 1.0f) * (float)XDIM - 1.0f) * 0.5f;
    float x0f = floorf(ix), y0f = floorf(iy);
    float wx = ix - x0f, wy = iy - y0f;
    #pragma unroll
    for (int r = 0; r < 16; r++) a[r] = 0.f;
    #pragma unroll
    for (int corner = 0; corner < 4; corner++) {
        float xf = x0f + (float)(corner & 1);
        float yf = y0f + (float)(corner >> 1);
        float w = ((corner & 1) ? wx : 1.f - wx) * ((corner >> 1) ? wy : 1.f - wy);
        bool valid = (xf >= 0.f) && (xf <= (float)(XDIM - 1)) &&
                     (yf >= 0.f) && (yf <= (float)(XDIM - 1));
        if (!valid) w = 0.f;
        int xi = (int)fminf(fmaxf(xf, 0.f), (float)(XDIM - 1));
        int yi = (int)fminf(fmaxf(yf, 0.f), (float)(XDIM - 1));
        const float* fp = yimg + (yi * XDIM + xi) * CDIM + 4 * h;
        #pragma unroll
        for (int g = 0; g < 4; g++) {
            f32x4 v = *(const f32x4*)(fp + 8 * g);
            #pragma unroll
            for (int i = 0; i < 4; i++)
                a[4 * g + i] = fmaf(w, v[i], a[4 * g + i]);
        }
    }
    // bias + relu of render layer 1 (r_bh[0]), exact fp32
    #pragma unroll
    for (int g = 0; g < 4; g++) {
        f32x4 bia = *(const f32x4*)(r_bh + 0 * CDIM + 8 * g + 4 * h);
        #pragma unroll
        for (int i = 0; i < 4; i++)
            a[4 * g + i] = fmaxf(a[4 * g + i] + bia[i], 0.f);
    }

    // ---- render layers 2,3 ----
    render_layer(a, r1h, r1l, r_bh + 1 * CDIM, h);
    render_layer(a, r2h, r2l, r_bh + 2 * CDIM, h);

    // ---- output head ----
    float o = 0.f;
    #pragma unroll
    for (int g = 0; g < 4; g++) {
        f32x4 wz = *(const f32x4*)(r_wo + 8 * g + 4 * h);
        #pragma unroll
        for (int i = 0; i < 4; i++) o = fmaf(a[4 * g + i], wz[i], o);
    }
    o += __shfl_xor(o, 32, 64);
    o += r_bo[0];
    o = (o >= 0.f) ? o : 0.001f * o;
    if (h == 0) out[b * NPIX + pix] = o;
}

extern "C" void kernel_launch(void* const* d_in, const int* in_sizes, int n_in,
                              void* d_out, int out_size, void* d_ws, size_t ws_size,
                              hipStream_t stream) {
    const float* t        = (const float*)d_in[0];
    const float* data     = (const float*)d_in[1];
    const float* lerp_w   = (const float*)d_in[2];
    const float* xy_basis = (const float*)d_in[3];
    const float* w_in     = (const float*)d_in[4];
    const float* b_in     = (const float*)d_in[5];
    const float* w_h      = (const float*)d_in[6];
    const float* b_h      = (const float*)d_in[7];
    const float* ln_g     = (const float*)d_in[8];
    const float* ln_b     = (const float*)d_in[9];
    const float* w_out    = (const float*)d_in[10];
    const float* b_out    = (const float*)d_in[11];
    const float* r_wh     = (const float*)d_in[12];
    const float* r_bh     = (const float*)d_in[13];
    const float* r_wo     = (const float*)d_in[14];
    const float* r_bo     = (const float*)d_in[15];
    const int* x0 = (const int*)d_in[16];
    const int* y0 = (const int*)d_in[17];
    const int* x1 = (const int*)d_in[18];
    const int* y1 = (const int*)d_in[19];

    float* feats = (float*)d_ws;   // becomes Y after y_kernel
    unsigned short* afrag = (unsigned short*)((char*)d_ws + FEATS_BYTES);
    float* out = (float*)d_out;

    wprep_kernel<<<12, 64, 0, stream>>>(w_h, r_wh, afrag);
    feats_kernel<<<(NPIX * CDIM) / 256, 256, 0, stream>>>(data, lerp_w, x0, y0, x1, y1, feats);
    y_kernel<<<(NPIX * CDIM) / 256, 256, 0, stream>>>(r_wh, feats);
    fused_mfma_kernel<<<(NB * NPIX) / 128, 256, 0, stream>>>(
        t, xy_basis, w_in, b_in, b_h, ln_g, ln_b, w_out, b_out,
        r_bh, r_wo, r_bo, feats, afrag, out);
}

// Round 9
// 375.345 us; speedup vs baseline: 1.7160x; 1.7160x over previous
//
#include <hip/hip_runtime.h>

#define XDIM 512
#define CDIM 32
#define NPIX (XDIM * XDIM)
#define NB 8

typedef short bf16x8 __attribute__((ext_vector_type(8)));
typedef float f32x4 __attribute__((ext_vector_type(4)));
typedef float f32x16 __attribute__((ext_vector_type(16)));

#define FEATS_BYTES (NPIX * CDIM * 4)   // 33.5 MB

__device__ __forceinline__ short f2bf(float v) {
    __bf16 b = (__bf16)v;
    return __builtin_bit_cast(short, b);
}
__device__ __forceinline__ float bfup(short s) {
    return (float)__builtin_bit_cast(__bf16, s);
}

// ---------------------------------------------------------------------------
// Weight prep (identical to R3/R5/R6). L=3 (render layer 1) unused by the
// hot kernel (folded into y_kernel) but kept for layout stability.
// ---------------------------------------------------------------------------
__global__ __launch_bounds__(64) void wprep_kernel(
    const float* __restrict__ w_h, const float* __restrict__ r_wh,
    unsigned short* __restrict__ afrag)
{
    int L = blockIdx.x >> 1;
    int T = blockIdx.x & 1;
    int l = threadIdx.x;
    const float* W = (L < 3) ? (w_h + L * CDIM * CDIM) : (r_wh + (L - 3) * CDIM * CDIM);
    int m = l & 31;
    int h = l >> 5;
    unsigned short* dh = afrag + (((L * 2 + T) * 2 + 0) * 64 + l) * 8;
    unsigned short* dl = afrag + (((L * 2 + T) * 2 + 1) * 64 + l) * 8;
    for (int j = 0; j < 8; j++) {
        int c = 16 * T + 4 * h + (j & 3) + 8 * (j >> 2);
        float v = W[c * CDIM + m];
        short hi = f2bf(v);
        short lo = f2bf(v - bfup(hi));
        dh[j] = (unsigned short)hi;
        dl[j] = (unsigned short)lo;
    }
}

__global__ __launch_bounds__(256) void feats_kernel(
    const float* __restrict__ data, const float* __restrict__ lerp_w,
    const int* __restrict__ x0, const int* __restrict__ y0,
    const int* __restrict__ x1, const int* __restrict__ y1,
    float* __restrict__ feats)
{
    int tid = blockIdx.x * 256 + threadIdx.x;
    int p = tid >> 5;
    int c = tid & 31;
    if (p >= NPIX) return;
    float wA = lerp_w[p * 2 + 0];
    float wB = lerp_w[p * 2 + 1];
    int xa = x0[p], ya = y0[p], xb = x1[p], yb = y1[p];
    float v00 = data[(ya * XDIM + xa) * CDIM + c];
    float v01 = data[(ya * XDIM + xb) * CDIM + c];
    float v10 = data[(yb * XDIM + xa) * CDIM + c];
    float v11 = data[(yb * XDIM + xb) * CDIM + c];
    float r = v00 * (1.f - wA) * (1.f - wB) + v01 * wA * (1.f - wB)
            + v10 * (1.f - wA) * wB + v11 * wA * wB;
    feats[p * CDIM + c] = r;
}

// ---------------------------------------------------------------------------
// Y-fold: feats[p] <- r_wh[0]^T @ feats[p], in place, exact fp32.
// Verified correct in R8 (absmax unchanged). After this, the bilinear
// gather's weighted sum IS render layer 1's pre-activation (linearity).
// ---------------------------------------------------------------------------
__global__ __launch_bounds__(256) void y_kernel(
    const float* __restrict__ r_wh, float* __restrict__ feats)
{
    int tid = blockIdx.x * 256 + threadIdx.x;
    int p = tid >> 5;
    int c = tid & 31;
    const float* f = feats + p * CDIM;
    float acc = 0.f;
    #pragma unroll
    for (int k = 0; k < CDIM; k++)
        acc = fmaf(f[k], r_wh[k * CDIM + c], acc);
    feats[p * CDIM + c] = acc;
}

// ---------------------------------------------------------------------------
// Hot kernel helpers — EXACT R6 versions (no setprio).
// ---------------------------------------------------------------------------
__device__ __forceinline__ void build2(const float a[16], bf16x8 bh[2], bf16x8 bl[2]) {
    #pragma unroll
    for (int r = 0; r < 16; r++) {
        short hi = f2bf(a[r]);
        bh[r >> 3][r & 7] = hi;
        bl[r >> 3][r & 7] = f2bf(a[r] - bfup(hi));
    }
}

__device__ __forceinline__ void matmul_split(
    const bf16x8 fh[2], const bf16x8 fl[2],
    const bf16x8 bh[2], const bf16x8 bl[2],
    f32x16& accA, f32x16& accB)
{
    f32x16 z = {0.f, 0.f, 0.f, 0.f, 0.f, 0.f, 0.f, 0.f,
                0.f, 0.f, 0.f, 0.f, 0.f, 0.f, 0.f, 0.f};
    accA = z; accB = z;
    accA = __builtin_amdgcn_mfma_f32_32x32x16_bf16(fl[0], bh[0], accA, 0, 0, 0);
    accB = __builtin_amdgcn_mfma_f32_32x32x16_bf16(fl[1], bh[1], accB, 0, 0, 0);
    accA = __builtin_amdgcn_mfma_f32_32x32x16_bf16(fh[0], bl[0], accA, 0, 0, 0);
    accB = __builtin_amdgcn_mfma_f32_32x32x16_bf16(fh[1], bl[1], accB, 0, 0, 0);
    accA = __builtin_amdgcn_mfma_f32_32x32x16_bf16(fh[0], bh[0], accA, 0, 0, 0);
    accB = __builtin_amdgcn_mfma_f32_32x32x16_bf16(fh[1], bh[1], accB, 0, 0, 0);
}

__device__ __forceinline__ void warp_layer(
    float a[16], const bf16x8 fh[2], const bf16x8 fl[2],
    const float* __restrict__ bias, const float* __restrict__ gamma,
    const float* __restrict__ beta, int h)
{
    bf16x8 bh[2], bl[2];
    build2(a, bh, bl);
    f32x16 accA, accB;
    matmul_split(fh, fl, bh, bl, accA, accB);

    float sum = 0.f, sq = 0.f;
    #pragma unroll
    for (int g = 0; g < 4; g++) {
        f32x4 bia = *(const f32x4*)(bias + 8 * g + 4 * h);
        #pragma unroll
        for (int i = 0; i < 4; i++) {
            int r = 4 * g + i;
            float v = (accA[r] + accB[r]) + bia[i];
            a[r] = v;
            sum += v;
            sq = fmaf(v, v, sq);
        }
    }
    sum += __shfl_xor(sum, 32, 64);
    sq  += __shfl_xor(sq, 32, 64);
    float mu = sum * (1.f / 32.f);
    float var = fmaf(sq, 1.f / 32.f, -mu * mu);
    float rs = rsqrtf(var + 1e-5f);
    #pragma unroll
    for (int g = 0; g < 4; g++) {
        f32x4 gg = *(const f32x4*)(gamma + 8 * g + 4 * h);
        f32x4 be = *(const f32x4*)(beta + 8 * g + 4 * h);
        #pragma unroll
        for (int i = 0; i < 4; i++) {
            int r = 4 * g + i;
            a[r] = __sinf(fmaf((a[r] - mu) * rs, gg[i], be[i]));
        }
    }
}

__device__ __forceinline__ void render_layer(
    float a[16], const bf16x8 fh[2], const bf16x8 fl[2],
    const float* __restrict__ bias, int h)
{
    bf16x8 bh[2], bl[2];
    build2(a, bh, bl);
    f32x16 accA, accB;
    matmul_split(fh, fl, bh, bl, accA, accB);
    #pragma unroll
    for (int g = 0; g < 4; g++) {
        f32x4 bia = *(const f32x4*)(bias + 8 * g + 4 * h);
        #pragma unroll
        for (int i = 0; i < 4; i++) {
            int r = 4 * g + i;
            a[r] = fmaxf((accA[r] + accB[r]) + bia[i], 0.f);
        }
    }
}

#define LOADFRAG(L, FH, FL) do { \
    FH[0] = ap[(((L) * 2 + 0) * 2 + 0) * 64 + lane]; \
    FL[0] = ap[(((L) * 2 + 0) * 2 + 1) * 64 + lane]; \
    FH[1] = ap[(((L) * 2 + 1) * 2 + 0) * 64 + lane]; \
    FL[1] = ap[(((L) * 2 + 1) * 2 + 1) * 64 + lane]; \
} while (0)

__global__ __launch_bounds__(256, 4) void fused_mfma_kernel(
    const float* __restrict__ t, const float* __restrict__ xy_basis,
    const float* __restrict__ w_in, const float* __restrict__ b_in,
    const float* __restrict__ b_h,
    const float* __restrict__ ln_g, const float* __restrict__ ln_b,
    const float* __restrict__ w_out, const float* __restrict__ b_out,
    const float* __restrict__ r_bh,
    const float* __restrict__ r_wo, const float* __restrict__ r_bo,
    const float* __restrict__ yimg, const unsigned short* __restrict__ afrag,
    float* __restrict__ out)
{
    int lane = threadIdx.x & 63;
    int p = lane & 31, h = lane >> 5;

    // XCD-chunked swizzle (identical to R3/R5/R6).
    int bid = blockIdx.x;
    int swz = (bid & 7) * 2048 + (bid >> 3);
    int gw = swz * 4 + (int)(threadIdx.x >> 6);
    int b = gw & 7;
    int pbase = (gw >> 3) << 5;
    int pix = pbase + p;

    const bf16x8* ap = (const bf16x8*)afrag;

    bf16x8 fAh[2], fAl[2], fBh[2], fBl[2], fCh[2], fCl[2];
    LOADFRAG(0, fAh, fAl);
    LOADFRAG(1, fBh, fBl);

    float alpha = t[b] + 0.5f;
    float2 xy = ((const float2*)xy_basis)[pix];

    // ---- input layer ----
    float a[16];
    #pragma unroll
    for (int g = 0; g < 4; g++) {
        int c = 8 * g + 4 * h;
        f32x4 w0 = *(const f32x4*)(w_in + c);
        f32x4 w1 = *(const f32x4*)(w_in + CDIM + c);
        f32x4 w2 = *(const f32x4*)(w_in + 2 * CDIM + c);
        f32x4 bb = *(const f32x4*)(b_in + c);
        #pragma unroll
        for (int i = 0; i < 4; i++)
            a[4 * g + i] = fmaf(xy.x, w0[i], fmaf(xy.y, w1[i], fmaf(alpha, w2[i], bb[i])));
    }

    // ---- 3 warp layers ----
    warp_layer(a, fAh, fAl, b_h + 0 * CDIM, ln_g + 0 * CDIM, ln_b + 0 * CDIM, h);
    LOADFRAG(2, fCh, fCl);
    warp_layer(a, fBh, fBl, b_h + 1 * CDIM, ln_g + 1 * CDIM, ln_b + 1 * CDIM, h);
    warp_layer(a, fCh, fCl, b_h + 2 * CDIM, ln_g + 2 * CDIM, ln_b + 2 * CDIM, h);

    // ---- motion head ----
    float mx = 0.f, my = 0.f;
    #pragma unroll
    for (int g = 0; g < 4; g++) {
        int c = 8 * g + 4 * h;
        f32x4 wa = *(const f32x4*)(w_out + 2 * c);
        f32x4 wb = *(const f32x4*)(w_out + 2 * c + 4);
        mx = fmaf(a[4 * g + 0], wa[0], mx); my = fmaf(a[4 * g + 0], wa[1], my);
        mx = fmaf(a[4 * g + 1], wa[2], mx); my = fmaf(a[4 * g + 1], wa[3], my);
        mx = fmaf(a[4 * g + 2], wb[0], mx); my = fmaf(a[4 * g + 2], wb[1], my);
        mx = fmaf(a[4 * g + 3], wb[2], mx); my = fmaf(a[4 * g + 3], wb[3], my);
    }
    mx += __shfl_xor(mx, 32, 64);
    my += __shfl_xor(my, 32, 64);
    float gridx = fmaf(mx + b_out[0], 0.1f, xy.x);
    float gridy = fmaf(my + b_out[1], 0.1f, xy.y);

    // ---- remaining render-layer fragments (L=4,5): overlap with gather ----
    bf16x8 r1h[2], r1l[2], r2h[2], r2l[2];
    LOADFRAG(4, r1h, r1l);
    LOADFRAG(5, r2h, r2l);

    // ---- gather on Y: weighted sum IS render layer 1's pre-activation ----
    float ix = ((gridx + 1.0f) * (float)XDIM - 1.0f) * 0.5f;
    float iy = ((gridy + 1.0f) * (float)XDIM - 1.0f) * 0.5f;
    float x0f = floorf(ix), y0f = floorf(iy);
    float wx = ix - x0f, wy = iy - y0f;
    #pragma unroll
    for (int r = 0; r < 16; r++) a[r] = 0.f;
    #pragma unroll
    for (int corner = 0; corner < 4; corner++) {
        float xf = x0f + (float)(corner & 1);
        float yf = y0f + (float)(corner >> 1);
        float w = ((corner & 1) ? wx : 1.f - wx) * ((corner >> 1) ? wy : 1.f - wy);
        bool valid = (xf >= 0.f) && (xf <= (float)(XDIM - 1)) &&
                     (yf >= 0.f) && (yf <= (float)(XDIM - 1));
        if (!valid) w = 0.f;
        int xi = (int)fminf(fmaxf(xf, 0.f), (float)(XDIM - 1));
        int yi = (int)fminf(fmaxf(yf, 0.f), (float)(XDIM - 1));
        const float* fp = yimg + (yi * XDIM + xi) * CDIM + 4 * h;
        #pragma unroll
        for (int g = 0; g < 4; g++) {
            f32x4 v = *(const f32x4*)(fp + 8 * g);
            #pragma unroll
            for (int i = 0; i < 4; i++)
                a[4 * g + i] = fmaf(w, v[i], a[4 * g + i]);
        }
    }
    // bias + relu of render layer 1 (r_bh[0]), exact fp32
    #pragma unroll
    for (int g = 0; g < 4; g++) {
        f32x4 bia = *(const f32x4*)(r_bh + 0 * CDIM + 8 * g + 4 * h);
        #pragma unroll
        for (int i = 0; i < 4; i++)
            a[4 * g + i] = fmaxf(a[4 * g + i] + bia[i], 0.f);
    }

    // ---- render layers 2,3 ----
    render_layer(a, r1h, r1l, r_bh + 1 * CDIM, h);
    render_layer(a, r2h, r2l, r_bh + 2 * CDIM, h);

    // ---- output head ----
    float o = 0.f;
    #pragma unroll
    for (int g = 0; g < 4; g++) {
        f32x4 wz = *(const f32x4*)(r_wo + 8 * g + 4 * h);
        #pragma unroll
        for (int i = 0; i < 4; i++) o = fmaf(a[4 * g + i], wz[i], o);
    }
    o += __shfl_xor(o, 32, 64);
    o += r_bo[0];
    o = (o >= 0.f) ? o : 0.001f * o;
    if (h == 0) out[b * NPIX + pix] = o;
}

extern "C" void kernel_launch(void* const* d_in, const int* in_sizes, int n_in,
                              void* d_out, int out_size, void* d_ws, size_t ws_size,
                              hipStream_t stream) {
    const float* t        = (const float*)d_in[0];
    const float* data     = (const float*)d_in[1];
    const float* lerp_w   = (const float*)d_in[2];
    const float* xy_basis = (const float*)d_in[3];
    const float* w_in     = (const float*)d_in[4];
    const float* b_in     = (const float*)d_in[5];
    const float* w_h      = (const float*)d_in[6];
    const float* b_h      = (const float*)d_in[7];
    const float* ln_g     = (const float*)d_in[8];
    const float* ln_b     = (const float*)d_in[9];
    const float* w_out    = (const float*)d_in[10];
    const float* b_out    = (const float*)d_in[11];
    const float* r_wh     = (const float*)d_in[12];
    const float* r_bh     = (const float*)d_in[13];
    const float* r_wo     = (const float*)d_in[14];
    const float* r_bo     = (const float*)d_in[15];
    const int* x0 = (const int*)d_in[16];
    const int* y0 = (const int*)d_in[17];
    const int* x1 = (const int*)d_in[18];
    const int* y1 = (const int*)d_in[19];

    float* feats = (float*)d_ws;   // becomes Y after y_kernel
    unsigned short* afrag = (unsigned short*)((char*)d_ws + FEATS_BYTES);
    float* out = (float*)d_out;

    wprep_kernel<<<12, 64, 0, stream>>>(w_h, r_wh, afrag);
    feats_kernel<<<(NPIX * CDIM) / 256, 256, 0, stream>>>(data, lerp_w, x0, y0, x1, y1, feats);
    y_kernel<<<(NPIX * CDIM) / 256, 256, 0, stream>>>(r_wh, feats);
    fused_mfma_kernel<<<(NB * NPIX) / 128, 256, 0, stream>>>(
        t, xy_basis, w_in, b_in, b_h, ln_g, ln_b, w_out, b_out,
        r_bh, r_wo, r_bo, feats, afrag, out);
}

// Round 10
// 270.055 us; speedup vs baseline: 2.3851x; 1.3899x over previous
//
#include <hip/hip_runtime.h>

#define XDIM 512
#define CDIM 32
#define NPIX (XDIM * XDIM)
#define NB 8

typedef short bf16x8 __attribute__((ext_vector_type(8)));
typedef float f32x4 __attribute__((ext_vector_type(4)));
typedef float f32x16 __attribute__((ext_vector_type(16)));

#define FEATS_BYTES (NPIX * CDIM * 4)   // 33.5 MB

__device__ __forceinline__ short f2bf(float v) {
    __bf16 b = (__bf16)v;
    return __builtin_bit_cast(short, b);
}
__device__ __forceinline__ float bfup(short s) {
    return (float)__builtin_bit_cast(__bf16, s);
}

// ---------------------------------------------------------------------------
// Weight prep (identical to R3/R5/R6).
// ---------------------------------------------------------------------------
__global__ __launch_bounds__(64) void wprep_kernel(
    const float* __restrict__ w_h, const float* __restrict__ r_wh,
    unsigned short* __restrict__ afrag)
{
    int L = blockIdx.x >> 1;
    int T = blockIdx.x & 1;
    int l = threadIdx.x;
    const float* W = (L < 3) ? (w_h + L * CDIM * CDIM) : (r_wh + (L - 3) * CDIM * CDIM);
    int m = l & 31;
    int h = l >> 5;
    unsigned short* dh = afrag + (((L * 2 + T) * 2 + 0) * 64 + l) * 8;
    unsigned short* dl = afrag + (((L * 2 + T) * 2 + 1) * 64 + l) * 8;
    for (int j = 0; j < 8; j++) {
        int c = 16 * T + 4 * h + (j & 3) + 8 * (j >> 2);
        float v = W[c * CDIM + m];
        short hi = f2bf(v);
        short lo = f2bf(v - bfup(hi));
        dh[j] = (unsigned short)hi;
        dl[j] = (unsigned short)lo;
    }
}

__global__ __launch_bounds__(256) void feats_kernel(
    const float* __restrict__ data, const float* __restrict__ lerp_w,
    const int* __restrict__ x0, const int* __restrict__ y0,
    const int* __restrict__ x1, const int* __restrict__ y1,
    float* __restrict__ feats)
{
    int tid = blockIdx.x * 256 + threadIdx.x;
    int p = tid >> 5;
    int c = tid & 31;
    if (p >= NPIX) return;
    float wA = lerp_w[p * 2 + 0];
    float wB = lerp_w[p * 2 + 1];
    int xa = x0[p], ya = y0[p], xb = x1[p], yb = y1[p];
    float v00 = data[(ya * XDIM + xa) * CDIM + c];
    float v01 = data[(ya * XDIM + xb) * CDIM + c];
    float v10 = data[(yb * XDIM + xa) * CDIM + c];
    float v11 = data[(yb * XDIM + xb) * CDIM + c];
    float r = v00 * (1.f - wA) * (1.f - wB) + v01 * wA * (1.f - wB)
            + v10 * (1.f - wA) * wB + v11 * wA * wB;
    feats[p * CDIM + c] = r;
}

// ---------------------------------------------------------------------------
// Hot kernel helpers — EXACT R6 versions (no setprio, no y-fold).
// ---------------------------------------------------------------------------
__device__ __forceinline__ void build2(const float a[16], bf16x8 bh[2], bf16x8 bl[2]) {
    #pragma unroll
    for (int r = 0; r < 16; r++) {
        short hi = f2bf(a[r]);
        bh[r >> 3][r & 7] = hi;
        bl[r >> 3][r & 7] = f2bf(a[r] - bfup(hi));
    }
}

__device__ __forceinline__ void matmul_split(
    const bf16x8 fh[2], const bf16x8 fl[2],
    const bf16x8 bh[2], const bf16x8 bl[2],
    f32x16& accA, f32x16& accB)
{
    f32x16 z = {0.f, 0.f, 0.f, 0.f, 0.f, 0.f, 0.f, 0.f,
                0.f, 0.f, 0.f, 0.f, 0.f, 0.f, 0.f, 0.f};
    accA = z; accB = z;
    accA = __builtin_amdgcn_mfma_f32_32x32x16_bf16(fl[0], bh[0], accA, 0, 0, 0);
    accB = __builtin_amdgcn_mfma_f32_32x32x16_bf16(fl[1], bh[1], accB, 0, 0, 0);
    accA = __builtin_amdgcn_mfma_f32_32x32x16_bf16(fh[0], bl[0], accA, 0, 0, 0);
    accB = __builtin_amdgcn_mfma_f32_32x32x16_bf16(fh[1], bl[1], accB, 0, 0, 0);
    accA = __builtin_amdgcn_mfma_f32_32x32x16_bf16(fh[0], bh[0], accA, 0, 0, 0);
    accB = __builtin_amdgcn_mfma_f32_32x32x16_bf16(fh[1], bh[1], accB, 0, 0, 0);
}

__device__ __forceinline__ void warp_layer(
    float a[16], const bf16x8 fh[2], const bf16x8 fl[2],
    const float* __restrict__ bias, const float* __restrict__ gamma,
    const float* __restrict__ beta, int h)
{
    bf16x8 bh[2], bl[2];
    build2(a, bh, bl);
    f32x16 accA, accB;
    matmul_split(fh, fl, bh, bl, accA, accB);

    float sum = 0.f, sq = 0.f;
    #pragma unroll
    for (int g = 0; g < 4; g++) {
        f32x4 bia = *(const f32x4*)(bias + 8 * g + 4 * h);
        #pragma unroll
        for (int i = 0; i < 4; i++) {
            int r = 4 * g + i;
            float v = (accA[r] + accB[r]) + bia[i];
            a[r] = v;
            sum += v;
            sq = fmaf(v, v, sq);
        }
    }
    sum += __shfl_xor(sum, 32, 64);
    sq  += __shfl_xor(sq, 32, 64);
    float mu = sum * (1.f / 32.f);
    float var = fmaf(sq, 1.f / 32.f, -mu * mu);
    float rs = rsqrtf(var + 1e-5f);
    #pragma unroll
    for (int g = 0; g < 4; g++) {
        f32x4 gg = *(const f32x4*)(gamma + 8 * g + 4 * h);
        f32x4 be = *(const f32x4*)(beta + 8 * g + 4 * h);
        #pragma unroll
        for (int i = 0; i < 4; i++) {
            int r = 4 * g + i;
            a[r] = __sinf(fmaf((a[r] - mu) * rs, gg[i], be[i]));
        }
    }
}

__device__ __forceinline__ void render_layer(
    float a[16], const bf16x8 fh[2], const bf16x8 fl[2],
    const float* __restrict__ bias, int h)
{
    bf16x8 bh[2], bl[2];
    build2(a, bh, bl);
    f32x16 accA, accB;
    matmul_split(fh, fl, bh, bl, accA, accB);
    #pragma unroll
    for (int g = 0; g < 4; g++) {
        f32x4 bia = *(const f32x4*)(bias + 8 * g + 4 * h);
        #pragma unroll
        for (int i = 0; i < 4; i++) {
            int r = 4 * g + i;
            a[r] = fmaxf((accA[r] + accB[r]) + bia[i], 0.f);
        }
    }
}

// motion head (exact R6 body)
__device__ __forceinline__ void motion_head(
    const float a[16], const float* __restrict__ w_out, int h,
    float& mxo, float& myo)
{
    float mx = 0.f, my = 0.f;
    #pragma unroll
    for (int g = 0; g < 4; g++) {
        int c = 8 * g + 4 * h;
        f32x4 wa = *(const f32x4*)(w_out + 2 * c);
        f32x4 wb = *(const f32x4*)(w_out + 2 * c + 4);
        mx = fmaf(a[4 * g + 0], wa[0], mx); my = fmaf(a[4 * g + 0], wa[1], my);
        mx = fmaf(a[4 * g + 1], wa[2], mx); my = fmaf(a[4 * g + 1], wa[3], my);
        mx = fmaf(a[4 * g + 2], wb[0], mx); my = fmaf(a[4 * g + 2], wb[1], my);
        mx = fmaf(a[4 * g + 3], wb[2], mx); my = fmaf(a[4 * g + 3], wb[3], my);
    }
    mx += __shfl_xor(mx, 32, 64);
    my += __shfl_xor(my, 32, 64);
    mxo = mx; myo = my;
}

// bilinear gather (exact R6 body)
__device__ __forceinline__ void do_gather(
    float a[16], float gridx, float gridy,
    const float* __restrict__ feats, int h)
{
    float ix = ((gridx + 1.0f) * (float)XDIM - 1.0f) * 0.5f;
    float iy = ((gridy + 1.0f) * (float)XDIM - 1.0f) * 0.5f;
    float x0f = floorf(ix), y0f = floorf(iy);
    float wx = ix - x0f, wy = iy - y0f;
    #pragma unroll
    for (int r = 0; r < 16; r++) a[r] = 0.f;
    #pragma unroll
    for (int corner = 0; corner < 4; corner++) {
        float xf = x0f + (float)(corner & 1);
        float yf = y0f + (float)(corner >> 1);
        float w = ((corner & 1) ? wx : 1.f - wx) * ((corner >> 1) ? wy : 1.f - wy);
        bool valid = (xf >= 0.f) && (xf <= (float)(XDIM - 1)) &&
                     (yf >= 0.f) && (yf <= (float)(XDIM - 1));
        if (!valid) w = 0.f;
        int xi = (int)fminf(fmaxf(xf, 0.f), (float)(XDIM - 1));
        int yi = (int)fminf(fmaxf(yf, 0.f), (float)(XDIM - 1));
        const float* fp = feats + (yi * XDIM + xi) * CDIM + 4 * h;
        #pragma unroll
        for (int g = 0; g < 4; g++) {
            f32x4 v = *(const f32x4*)(fp + 8 * g);
            #pragma unroll
            for (int i = 0; i < 4; i++)
                a[4 * g + i] = fmaf(w, v[i], a[4 * g + i]);
        }
    }
}

__device__ __forceinline__ float out_head(
    const float a[16], const float* __restrict__ r_wo, int h)
{
    float o = 0.f;
    #pragma unroll
    for (int g = 0; g < 4; g++) {
        f32x4 wz = *(const f32x4*)(r_wo + 8 * g + 4 * h);
        #pragma unroll
        for (int i = 0; i < 4; i++) o = fmaf(a[4 * g + i], wz[i], o);
    }
    o += __shfl_xor(o, 32, 64);
    return o;
}

#define LOADFRAG(L, FH, FL) do { \
    FH[0] = ap[(((L) * 2 + 0) * 2 + 0) * 64 + lane]; \
    FL[0] = ap[(((L) * 2 + 0) * 2 + 1) * 64 + lane]; \
    FH[1] = ap[(((L) * 2 + 1) * 2 + 0) * 64 + lane]; \
    FL[1] = ap[(((L) * 2 + 1) * 2 + 1) * 64 + lane]; \
} while (0)

// ---------------------------------------------------------------------------
// Fused kernel, DUAL BATCH per wave: 32 pixels x batches {bp, bp+4}.
// Per-batch math is the exact R6 helper path -> bit-identical results.
// Two independent chains give the scheduler real ILP; frags/params amortized.
// ---------------------------------------------------------------------------
__global__ __launch_bounds__(256) void fused_mfma_kernel(
    const float* __restrict__ t, const float* __restrict__ xy_basis,
    const float* __restrict__ w_in, const float* __restrict__ b_in,
    const float* __restrict__ b_h,
    const float* __restrict__ ln_g, const float* __restrict__ ln_b,
    const float* __restrict__ w_out, const float* __restrict__ b_out,
    const float* __restrict__ r_bh,
    const float* __restrict__ r_wo, const float* __restrict__ r_bo,
    const float* __restrict__ feats, const unsigned short* __restrict__ afrag,
    float* __restrict__ out)
{
    int lane = threadIdx.x & 63;
    int p = lane & 31, h = lane >> 5;

    // XCD-chunked swizzle: 8192 blocks, 1024/XCD -> 1024 contiguous pixel
    // groups per XCD (all 8 batches) -> 4.2MB feats slice L2-resident.
    int bid = blockIdx.x;
    int swz = (bid & 7) * 1024 + (bid >> 3);
    int gw = swz * 4 + (int)(threadIdx.x >> 6);
    int bp = gw & 3;
    int b0 = bp, b1 = bp + 4;
    int pbase = (gw >> 2) << 5;
    int pix = pbase + p;

    const bf16x8* ap = (const bf16x8*)afrag;

    bf16x8 fAh[2], fAl[2], fBh[2], fBl[2], fCh[2], fCl[2];
    LOADFRAG(0, fAh, fAl);
    LOADFRAG(1, fBh, fBl);

    float alpha0 = t[b0] + 0.5f;
    float alpha1 = t[b1] + 0.5f;
    float2 xy = ((const float2*)xy_basis)[pix];

    // ---- input layer, each batch in exact R6 op order ----
    float a0[16], a1[16];
    #pragma unroll
    for (int g = 0; g < 4; g++) {
        int c = 8 * g + 4 * h;
        f32x4 w0 = *(const f32x4*)(w_in + c);
        f32x4 w1 = *(const f32x4*)(w_in + CDIM + c);
        f32x4 w2 = *(const f32x4*)(w_in + 2 * CDIM + c);
        f32x4 bb = *(const f32x4*)(b_in + c);
        #pragma unroll
        for (int i = 0; i < 4; i++) {
            a0[4 * g + i] = fmaf(xy.x, w0[i], fmaf(xy.y, w1[i], fmaf(alpha0, w2[i], bb[i])));
            a1[4 * g + i] = fmaf(xy.x, w0[i], fmaf(xy.y, w1[i], fmaf(alpha1, w2[i], bb[i])));
        }
    }

    // ---- 3 warp layers x 2 batches (independent chains) ----
    warp_layer(a0, fAh, fAl, b_h + 0 * CDIM, ln_g + 0 * CDIM, ln_b + 0 * CDIM, h);
    warp_layer(a1, fAh, fAl, b_h + 0 * CDIM, ln_g + 0 * CDIM, ln_b + 0 * CDIM, h);
    LOADFRAG(2, fCh, fCl);
    warp_layer(a0, fBh, fBl, b_h + 1 * CDIM, ln_g + 1 * CDIM, ln_b + 1 * CDIM, h);
    warp_layer(a1, fBh, fBl, b_h + 1 * CDIM, ln_g + 1 * CDIM, ln_b + 1 * CDIM, h);
    warp_layer(a0, fCh, fCl, b_h + 2 * CDIM, ln_g + 2 * CDIM, ln_b + 2 * CDIM, h);
    warp_layer(a1, fCh, fCl, b_h + 2 * CDIM, ln_g + 2 * CDIM, ln_b + 2 * CDIM, h);

    // ---- motion heads ----
    float mx0, my0, mx1, my1;
    motion_head(a0, w_out, h, mx0, my0);
    motion_head(a1, w_out, h, mx1, my1);
    float bo0 = b_out[0], bo1 = b_out[1];
    float gx0 = fmaf(mx0 + bo0, 0.1f, xy.x);
    float gy0 = fmaf(my0 + bo1, 0.1f, xy.y);
    float gx1 = fmaf(mx1 + bo0, 0.1f, xy.x);
    float gy1 = fmaf(my1 + bo1, 0.1f, xy.y);

    // ---- render fragments (L=3,4,5): issued before the gathers ----
    bf16x8 r0h[2], r0l[2], r1h[2], r1l[2], r2h[2], r2l[2];
    LOADFRAG(3, r0h, r0l);
    LOADFRAG(4, r1h, r1l);
    LOADFRAG(5, r2h, r2l);

    // ---- gathers (independent) ----
    do_gather(a0, gx0, gy0, feats, h);
    do_gather(a1, gx1, gy1, feats, h);

    // ---- 3 render layers x 2 batches ----
    render_layer(a0, r0h, r0l, r_bh + 0 * CDIM, h);
    render_layer(a1, r0h, r0l, r_bh + 0 * CDIM, h);
    render_layer(a0, r1h, r1l, r_bh + 1 * CDIM, h);
    render_layer(a1, r1h, r1l, r_bh + 1 * CDIM, h);
    render_layer(a0, r2h, r2l, r_bh + 2 * CDIM, h);
    render_layer(a1, r2h, r2l, r_bh + 2 * CDIM, h);

    // ---- output heads ----
    float o0 = out_head(a0, r_wo, h);
    float o1 = out_head(a1, r_wo, h);
    float rbo = r_bo[0];
    o0 += rbo; o1 += rbo;
    o0 = (o0 >= 0.f) ? o0 : 0.001f * o0;
    o1 = (o1 >= 0.f) ? o1 : 0.001f * o1;
    if (h == 0) {
        out[b0 * NPIX + pix] = o0;
        out[b1 * NPIX + pix] = o1;
    }
}

extern "C" void kernel_launch(void* const* d_in, const int* in_sizes, int n_in,
                              void* d_out, int out_size, void* d_ws, size_t ws_size,
                              hipStream_t stream) {
    const float* t        = (const float*)d_in[0];
    const float* data     = (const float*)d_in[1];
    const float* lerp_w   = (const float*)d_in[2];
    const float* xy_basis = (const float*)d_in[3];
    const float* w_in     = (const float*)d_in[4];
    const float* b_in     = (const float*)d_in[5];
    const float* w_h      = (const float*)d_in[6];
    const float* b_h      = (const float*)d_in[7];
    const float* ln_g     = (const float*)d_in[8];
    const float* ln_b     = (const float*)d_in[9];
    const float* w_out    = (const float*)d_in[10];
    const float* b_out    = (const float*)d_in[11];
    const float* r_wh     = (const float*)d_in[12];
    const float* r_bh     = (const float*)d_in[13];
    const float* r_wo     = (const float*)d_in[14];
    const float* r_bo     = (const float*)d_in[15];
    const int* x0 = (const int*)d_in[16];
    const int* y0 = (const int*)d_in[17];
    const int* x1 = (const int*)d_in[18];
    const int* y1 = (const int*)d_in[19];

    float* feats = (float*)d_ws;
    unsigned short* afrag = (unsigned short*)((char*)d_ws + FEATS_BYTES);
    float* out = (float*)d_out;

    wprep_kernel<<<12, 64, 0, stream>>>(w_h, r_wh, afrag);
    feats_kernel<<<(NPIX * CDIM) / 256, 256, 0, stream>>>(data, lerp_w, x0, y0, x1, y1, feats);
    fused_mfma_kernel<<<(NB * NPIX) / 256, 256, 0, stream>>>(
        t, xy_basis, w_in, b_in, b_h, ln_g, ln_b, w_out, b_out,
        r_bh, r_wo, r_bo, feats, afrag, out);
}